// Round 6
// baseline (210.018 us; speedup 1.0000x reference)
//
#include <hip/hip_runtime.h>

// Problem constants
#define INC    256
#define HIN    56
#define WIN    56
#define HOUT   19
#define WOUT   58
#define KTOT   768          // K = kh*256 + c; 24 MFMA K-steps (ks), 2 chunks x 12

typedef short frag8 __attribute__((ext_vector_type(8)));   // 8 bf16 bits (4 VGPRs)
typedef float f32x4 __attribute__((ext_vector_type(4)));   // MFMA accumulator

static __device__ __forceinline__ unsigned short f2bf(float f) {
    unsigned u = __float_as_uint(f);
    u += 0x7fffu + ((u >> 16) & 1u);      // round-to-nearest-even
    return (unsigned short)(u >> 16);
}

// ---------------------------------------------------------------------------
// prep_weff: fold sparse einsum into dense conv weights, emitted in MFMA
// A-fragment-linear order:
//   element (o, k):  o_tile=o>>4, m=o&15, ks=k>>5, kc=(k>>3)&3, j=k&7
//   Asw[(((o_tile*24 + ks)*64) + kc*16 + m)*8 + j]
//     = coeff[i(c),o] * lego[idx[i(c),o]][c&63][kh]           (bf16)
// ---------------------------------------------------------------------------
__global__ __launch_bounds__(256) void prep_weff(
    const float* __restrict__ lego,    // [64][64][3]
    const float* __restrict__ coefs,   // [4][256][64]
    const float* __restrict__ comb,    // [4][256][64]
    unsigned short* __restrict__ Asw)  // [16][24][64][8] bf16 bits
{
    __shared__ int   idxS[4];
    __shared__ float cofS[4];
    const int t  = threadIdx.x;
    const int kx = blockIdx.x;         // 0..2
    const int o  = blockIdx.y;         // 0..255
    const int wv = t >> 6, l = t & 63;

    float v  = comb[(wv * 256 + o) * 64 + l];
    int   bi = l;
    #pragma unroll
    for (int off = 32; off >= 1; off >>= 1) {
        float ov = __shfl_xor(v, off, 64);
        int   oi = __shfl_xor(bi, off, 64);
        if (ov > v || (ov == v && oi < bi)) { v = ov; bi = oi; }
    }
    if (l == 0) {
        idxS[wv] = bi;
        cofS[wv] = coefs[(wv * 256 + o) * 64 + bi];
    }
    __syncthreads();

    const int k  = kx * 256 + t;       // 0..767
    const int kh = k >> 8, c = k & 255;
    const int i  = c >> 6, cl = c & 63;
    float w = cofS[i] * lego[idxS[i] * 192 + cl * 3 + kh];

    const int o_tile = o >> 4, m = o & 15;
    const int ks = k >> 5, kc = (k >> 3) & 3, j = k & 7;
    Asw[((((size_t)o_tile * 24 + ks) * 64) + kc * 16 + m) * 8 + j] = f2bf(w);
}

// ---------------------------------------------------------------------------
// conv_mfma: dense 256x768 conv-GEMM per (w-half, h, b) block; 1216 blocks,
// 256 threads (4 waves). Out tile 256 o x 32 w. K in 2 chunks of 384.
//
// Pipeline (the R5 fix — staging was MLP-starved at 8 loads in flight):
//   issue 48 chunk0 loads -> pack/write -> sync ->
//   issue 48 chunk1 loads -> MFMA chunk0 (HBM latency hidden) -> sync ->
//   pack/write chunk1 -> sync -> MFMA chunk1 (A depth-1 prefetch) -> store.
// Register budget vs __launch_bounds__(256,5) cap (~100 arch VGPRs, acc in
// AGPRs): chunk0-MFMA live = v[48]+a[16]+b[8]+misc ~ 87 (no A-prefetch);
// chunk1-MFMA live = a+an+b ~ 56 (with A-prefetch).
// Layouts unchanged from R4/R5: 0 LDS bank conflicts measured.
// ---------------------------------------------------------------------------
__global__ __launch_bounds__(256, 5) void conv_mfma(
    const float* __restrict__ x,             // [32][256][56][56]
    const unsigned short* __restrict__ Asw,  // [16][24][64][8]
    float* __restrict__ out)                 // [32][256][19][58]
{
    __shared__ unsigned short Xs[12 * 2 * 64 * 8];   // 24 KB, B-frag-linear

    const int t  = threadIdx.x;
    const int wh = blockIdx.x;               // 0/1 w-half
    const int h  = blockIdx.y;               // 0..18
    const int b  = blockIdx.z;               // 0..31

    const int l  = t & 63;
    const int lo = l & 15;
    const int hi = l >> 4;
    const int wv = t >> 6;

    // staging mapping: thread (w = t&31, kg = t>>5); task p = kg*6+q ->
    // ksl = p>>2 (0..11), kc = p&3, k = c2*384 + ksl*32 + kc*8 + j
    const float* xb = x + (size_t)b * (INC * HIN * WIN);
    const int w     = t & 31;
    const int kg    = t >> 5;
    const int col   = wh * 32 - 1 + w;
    const bool colok = (unsigned)col < (unsigned)WIN;
    const int wtile = w >> 4;
    const int lbase = w & 15;
    const int rowbase = 3 * h - 1;

    const frag8* Af = (const frag8*)Asw + ((size_t)(wv * 4) * 24) * 64 + l;
    const frag8* Xf = (const frag8*)Xs + l;

    f32x4 acc[4][2];
    #pragma unroll
    for (int ot = 0; ot < 4; ++ot)
        #pragma unroll
        for (int nt = 0; nt < 2; ++nt)
            acc[ot][nt] = (f32x4){0.f, 0.f, 0.f, 0.f};

    float v[48];
    bool  okq[6];
    const float* xpq[6];

    // ---- issue ALL chunk0 loads (48 outstanding, safe base for OOB) ----
    #pragma unroll
    for (int q = 0; q < 6; ++q) {
        int p = kg * 6 + q, ksl = p >> 2, kc = p & 3;
        int kk = ksl * 32 + kc * 8;          // chunk0 k-base
        int kh = kk >> 8, c0 = kk & 255;
        int row = rowbase + kh;
        bool ok = colok && ((unsigned)row < (unsigned)HIN);
        okq[q]  = ok;
        xpq[q]  = ok ? (xb + (size_t)c0 * (HIN * WIN) + row * WIN + col) : xb;
    }
    #pragma unroll
    for (int q = 0; q < 6; ++q)
        #pragma unroll
        for (int j = 0; j < 8; ++j)
            v[q * 8 + j] = xpq[q][(size_t)j * (HIN * WIN)];

    // ---- pack & write chunk0 ----
    #pragma unroll
    for (int q = 0; q < 6; ++q) {
        int p = kg * 6 + q, ksl = p >> 2, kc = p & 3;
        union { frag8 f; unsigned short u[8]; } pk;
        #pragma unroll
        for (int j = 0; j < 8; ++j)
            pk.u[j] = f2bf(okq[q] ? v[q * 8 + j] : 0.f);
        *(frag8*)&Xs[(((ksl * 2 + wtile) * 64) + kc * 16 + lbase) * 8] = pk.f;
    }
    __syncthreads();

    // ---- issue ALL chunk1 loads (in flight across chunk0's MFMA) ----
    #pragma unroll
    for (int q = 0; q < 6; ++q) {
        int p = kg * 6 + q, ksl = p >> 2, kc = p & 3;
        int kk = 384 + ksl * 32 + kc * 8;    // chunk1 k-base
        int kh = kk >> 8, c0 = kk & 255;
        int row = rowbase + kh;
        bool ok = colok && ((unsigned)row < (unsigned)HIN);
        okq[q]  = ok;
        xpq[q]  = ok ? (xb + (size_t)c0 * (HIN * WIN) + row * WIN + col) : xb;
    }
    #pragma unroll
    for (int q = 0; q < 6; ++q)
        #pragma unroll
        for (int j = 0; j < 8; ++j)
            v[q * 8 + j] = xpq[q][(size_t)j * (HIN * WIN)];

    // ---- MFMA chunk0 (no A-prefetch: keeps arch-VGPR under the cap) ----
    frag8 a[4], an[4];
    #pragma unroll
    for (int ks = 0; ks < 12; ++ks) {
        #pragma unroll
        for (int ot = 0; ot < 4; ++ot) a[ot] = Af[(ot * 24 + ks) * 64];
        frag8 b0 = Xf[(ks * 2) * 64];
        frag8 b1 = Xf[(ks * 2 + 1) * 64];
        #pragma unroll
        for (int ot = 0; ot < 4; ++ot) {
            acc[ot][0] = __builtin_amdgcn_mfma_f32_16x16x32_bf16(a[ot], b0, acc[ot][0], 0, 0, 0);
            acc[ot][1] = __builtin_amdgcn_mfma_f32_16x16x32_bf16(a[ot], b1, acc[ot][1], 0, 0, 0);
        }
    }
    __syncthreads();                         // all waves done reading chunk0

    // ---- pack & write chunk1 (loads long since landed) ----
    #pragma unroll
    for (int q = 0; q < 6; ++q) {
        int p = kg * 6 + q, ksl = p >> 2, kc = p & 3;
        union { frag8 f; unsigned short u[8]; } pk;
        #pragma unroll
        for (int j = 0; j < 8; ++j)
            pk.u[j] = f2bf(okq[q] ? v[q * 8 + j] : 0.f);
        *(frag8*)&Xs[(((ksl * 2 + wtile) * 64) + kc * 16 + lbase) * 8] = pk.f;
    }
    __syncthreads();

    // ---- MFMA chunk1 (depth-1 A-prefetch; no v[] live) ----
    #pragma unroll
    for (int ot = 0; ot < 4; ++ot) a[ot] = Af[(ot * 24 + 12) * 64];
    #pragma unroll
    for (int ks = 12; ks < 24; ++ks) {
        frag8 b0 = Xf[((ks - 12) * 2) * 64];
        frag8 b1 = Xf[((ks - 12) * 2 + 1) * 64];
        if (ks < 23) {
            #pragma unroll
            for (int ot = 0; ot < 4; ++ot) an[ot] = Af[(ot * 24 + ks + 1) * 64];
        }
        #pragma unroll
        for (int ot = 0; ot < 4; ++ot) {
            acc[ot][0] = __builtin_amdgcn_mfma_f32_16x16x32_bf16(a[ot], b0, acc[ot][0], 0, 0, 0);
            acc[ot][1] = __builtin_amdgcn_mfma_f32_16x16x32_bf16(a[ot], b1, acc[ot][1], 0, 0, 0);
        }
        if (ks < 23) {
            #pragma unroll
            for (int ot = 0; ot < 4; ++ot) a[ot] = an[ot];
        }
    }

    // ---- store: D col = lo (w), row = hi*4 + r (o within 16-tile) ----
    const int wb = wh * 32;
    const int obase = wv * 64;
    #pragma unroll
    for (int ot = 0; ot < 4; ++ot) {
        #pragma unroll
        for (int nt = 0; nt < 2; ++nt) {
            int wcol = wb + nt * 16 + lo;
            if (wcol < WOUT) {
                #pragma unroll
                for (int r = 0; r < 4; ++r) {
                    int o = obase + ot * 16 + hi * 4 + r;
                    out[((size_t)(b * 256 + o) * HOUT + h) * WOUT + wcol] = acc[ot][nt][r];
                }
            }
        }
    }
}

extern "C" void kernel_launch(void* const* d_in, const int* in_sizes, int n_in,
                              void* d_out, int out_size, void* d_ws, size_t ws_size,
                              hipStream_t stream) {
    const float* x     = (const float*)d_in[0];   // (32,256,56,56)
    const float* lego  = (const float*)d_in[1];   // (64,64,3,1)
    const float* coefs = (const float*)d_in[2];   // (4,256,64,1,1)
    const float* comb  = (const float*)d_in[3];   // (4,256,64,1,1)
    float* out = (float*)d_out;                   // (32,256,19,58)

    unsigned short* Asw = (unsigned short*)d_ws;  // 196,608 bf16 = 384 KB

    prep_weff<<<dim3(3, 256), 256, 0, stream>>>(lego, coefs, comb, Asw);
    conv_mfma<<<dim3(2, HOUT, 32), 256, 0, stream>>>(x, Asw, out);
}